// Round 2
// baseline (328.518 us; speedup 1.0000x reference)
//
#include <hip/hip_runtime.h>
#include <math.h>

#define BB 16
#define HH 256
#define WW 256
#define NN (BB*HH*WW)

static __device__ constexpr float INF_EDT = 131072.0f; // H*H + W*W, exact in fp32

__device__ __forceinline__ float sigmoidf(float v){ return 1.0f/(1.0f+expf(-v)); }
// stable log_sigmoid(v) = min(v,0) - log1p(exp(-|v|))
__device__ __forceinline__ float logsigf(float v){
  return fminf(v, 0.0f) - log1pf(expf(-fabsf(v)));
}

__global__ void init_ws_k(float* __restrict__ acc, int* __restrict__ has_pos){
  int t = threadIdx.x;
  if (t < 8)  acc[t] = 0.0f;
  if (t < BB) has_pos[t] = 0;
}

// Pass 1: per (b, column j): g(x,j) = min_i f(i,j) + (x-i)^2
// gA: seeds = pos (t>0.5)  -> feeds d_in
// gB: seeds = ~pos         -> feeds d_out   (f_neg = INF - f_pos, exact)
__global__ __launch_bounds__(256) void edt_pass1(const float* __restrict__ tgt,
                                                 float* __restrict__ gA,
                                                 float* __restrict__ gB,
                                                 int* __restrict__ has_pos){
  __shared__ __align__(16) float fp[HH];
  __shared__ int any_s;
  const int b = blockIdx.x >> 8;
  const int j = blockIdx.x & 255;
  const int tid = threadIdx.x;
  if (tid == 0) any_s = 0;
  __syncthreads();
  const float tv = tgt[(b*HH + tid)*WW + j];
  const bool m = tv > 0.5f;
  fp[tid] = m ? 0.0f : INF_EDT;
  if (m) any_s = 1;              // benign same-value race
  __syncthreads();
  if (tid == 0 && any_s) atomicOr(&has_pos[b], 1);

  const float x = (float)tid;
  float gp = 3.4e38f, gn = 3.4e38f;
  const float4* fp4 = (const float4*)fp;
  #pragma unroll 4
  for (int i4 = 0; i4 < HH/4; ++i4){
    float4 v = fp4[i4];          // broadcast read, conflict-free
    float base = x - (float)(4*i4);
    float d0 = base*base;
    float e1 = base - 1.0f, d1 = e1*e1;
    float e2 = base - 2.0f, d2 = e2*e2;
    float e3 = base - 3.0f, d3 = e3*e3;
    gp = fminf(gp, v.x + d0);
    gp = fminf(gp, v.y + d1);
    gp = fminf(gp, v.z + d2);
    gp = fminf(gp, v.w + d3);
    gn = fminf(gn, (d0 + INF_EDT) - v.x);
    gn = fminf(gn, (d1 + INF_EDT) - v.y);
    gn = fminf(gn, (d2 + INF_EDT) - v.z);
    gn = fminf(gn, (d3 + INF_EDT) - v.w);
  }
  const int o = (b*HH + tid)*WW + j;
  gA[o] = gp;
  gB[o] = gn;
}

// Pass 2: per (b, row x): d2(x,y) = min_j g(x,j) + (y-j)^2 ; fused focal/ce/boundary.
__global__ __launch_bounds__(256) void edt_pass2_fused(const float* __restrict__ inp,
    const float* __restrict__ tgt, const float* __restrict__ gA, const float* __restrict__ gB,
    const int* __restrict__ has_pos, float* __restrict__ acc){
  __shared__ __align__(16) float ga_s[WW];
  __shared__ __align__(16) float gb_s[WW];
  __shared__ float red[3][4];
  const int b = blockIdx.x >> 8;
  const int x = blockIdx.x & 255;
  const int tid = threadIdx.x;   // y
  const int rowbase = (b*HH + x)*WW;
  ga_s[tid] = gA[rowbase + tid];
  gb_s[tid] = gB[rowbase + tid];
  __syncthreads();

  float dp = 3.4e38f, dn = 3.4e38f;
  const float y = (float)tid;
  const float4* ga4 = (const float4*)ga_s;
  const float4* gb4 = (const float4*)gb_s;
  #pragma unroll 4
  for (int j4 = 0; j4 < WW/4; ++j4){
    float4 va = ga4[j4];
    float4 vb = gb4[j4];
    float base = y - (float)(4*j4);
    float d0 = base*base;
    float e1 = base - 1.0f, d1 = e1*e1;
    float e2 = base - 2.0f, d2 = e2*e2;
    float e3 = base - 3.0f, d3 = e3*e3;
    dp = fminf(dp, va.x + d0); dn = fminf(dn, vb.x + d0);
    dp = fminf(dp, va.y + d1); dn = fminf(dn, vb.y + d1);
    dp = fminf(dp, va.z + d2); dn = fminf(dn, vb.z + d2);
    dp = fminf(dp, va.w + d3); dn = fminf(dn, vb.w + d3);
  }

  const float xv = inp[rowbase + tid];
  const float tv = tgt[rowbase + tid];
  const float sg = sigmoidf(xv);
  float sdf = sqrtf(dn) - sqrtf(dp);      // d_out - d_in
  sdf = has_pos[b] ? sdf : 0.0f;
  const float bnd = (sg - tv) * sdf;

  const float lp = logsigf(xv);
  const float ln = logsigf(-xv);
  const float bce = -(tv*lp + (1.0f - tv)*ln);
  const float pt = expf(-bce);
  const float om = 1.0f - pt;
  const float foc = 0.8f * om * om * bce;   // ALPHA=0.8, GAMMA=2
  // ce with POS_W=1 == bce

  float v0 = foc, v1 = bce, v2 = bnd;
  #pragma unroll
  for (int o = 32; o > 0; o >>= 1){
    v0 += __shfl_down(v0, o);
    v1 += __shfl_down(v1, o);
    v2 += __shfl_down(v2, o);
  }
  const int lane = tid & 63, wid = tid >> 6;
  if (lane == 0){ red[0][wid]=v0; red[1][wid]=v1; red[2][wid]=v2; }
  __syncthreads();
  if (tid == 0){
    atomicAdd(&acc[0], red[0][0]+red[0][1]+red[0][2]+red[0][3]);
    atomicAdd(&acc[1], red[1][0]+red[1][1]+red[1][2]+red[1][3]);
    atomicAdd(&acc[2], red[2][0]+red[2][1]+red[2][2]+red[2][3]);
  }
}

// Sobel edge term: mean |S(sigmoid(x)) - S(t)| with replicate padding.
__global__ __launch_bounds__(256) void sobel_edge_k(const float* __restrict__ inp,
    const float* __restrict__ tgt, float* __restrict__ acc){
  __shared__ float red[4];
  const int id = blockIdx.x*256 + threadIdx.x;
  const int b = id >> 16;
  const int r = (id >> 8) & 255;
  const int c = id & 255;
  const float* xb = inp + (b << 16);
  const float* tb = tgt + (b << 16);
  const int rm = r > 0 ? r-1 : 0, rp = r < 255 ? r+1 : 255;
  const int cm = c > 0 ? c-1 : 0, cp = c < 255 ? c+1 : 255;

  float s00 = sigmoidf(xb[rm*WW+cm]), s01 = sigmoidf(xb[rm*WW+c]), s02 = sigmoidf(xb[rm*WW+cp]);
  float s10 = sigmoidf(xb[ r*WW+cm]),                              s12 = sigmoidf(xb[ r*WW+cp]);
  float s20 = sigmoidf(xb[rp*WW+cm]), s21 = sigmoidf(xb[rp*WW+c]), s22 = sigmoidf(xb[rp*WW+cp]);
  float gxs = ((s02 - s00) + 2.0f*(s12 - s10) + (s22 - s20)) * 0.125f;
  float gys = ((s20 - s00) + 2.0f*(s21 - s01) + (s22 - s02)) * 0.125f;
  float mags = sqrtf(gxs*gxs + gys*gys + 1e-6f);

  float t00 = tb[rm*WW+cm], t01 = tb[rm*WW+c], t02 = tb[rm*WW+cp];
  float t10 = tb[ r*WW+cm],                    t12 = tb[ r*WW+cp];
  float t20 = tb[rp*WW+cm], t21 = tb[rp*WW+c], t22 = tb[rp*WW+cp];
  float gxt = ((t02 - t00) + 2.0f*(t12 - t10) + (t22 - t20)) * 0.125f;
  float gyt = ((t20 - t00) + 2.0f*(t21 - t01) + (t22 - t02)) * 0.125f;
  float magt = sqrtf(gxt*gxt + gyt*gyt + 1e-6f);

  float v = fabsf(mags - magt);
  #pragma unroll
  for (int o = 32; o > 0; o >>= 1) v += __shfl_down(v, o);
  if ((threadIdx.x & 63) == 0) red[threadIdx.x >> 6] = v;
  __syncthreads();
  if (threadIdx.x == 0) atomicAdd(&acc[3], red[0]+red[1]+red[2]+red[3]);
}

__global__ void finalize_k(const float* __restrict__ acc, float* __restrict__ out){
  out[0] = (acc[0] + acc[1] + acc[2] + acc[3]) * (1.0f/(float)NN);
}

extern "C" void kernel_launch(void* const* d_in, const int* in_sizes, int n_in,
                              void* d_out, int out_size, void* d_ws, size_t ws_size,
                              hipStream_t stream){
  const float* inp = (const float*)d_in[0];
  const float* tgt = (const float*)d_in[1];
  float* out = (float*)d_out;
  float* gA  = (float*)d_ws;          // B*H*W fp32, seeds = pos
  float* gB  = gA + NN;               // B*H*W fp32, seeds = ~pos
  float* acc = gB + NN;               // [focal, ce(bce), boundary, edge]
  int* has_pos = (int*)(acc + 8);     // B ints

  init_ws_k<<<1, 64, 0, stream>>>(acc, has_pos);
  edt_pass1<<<BB*WW, 256, 0, stream>>>(tgt, gA, gB, has_pos);
  edt_pass2_fused<<<BB*HH, 256, 0, stream>>>(inp, tgt, gA, gB, has_pos, acc);
  sobel_edge_k<<<NN/256, 256, 0, stream>>>(inp, tgt, acc);
  finalize_k<<<1, 1, 0, stream>>>(acc, out);
}

// Round 3
// 211.343 us; speedup vs baseline: 1.5544x; 1.5544x over previous
//
#include <hip/hip_runtime.h>
#include <math.h>

#define BB 16
#define HH 256
#define WW 256
#define NN (BB*HH*WW)

static __device__ constexpr float INF_EDT = 131072.0f; // H*H + W*W, exact in fp32

__device__ __forceinline__ float sigmoidf(float v){ return 1.0f/(1.0f+expf(-v)); }
// stable log_sigmoid(v) = min(v,0) - log1p(exp(-|v|))
__device__ __forceinline__ float logsigf(float v){
  return fminf(v, 0.0f) - log1pf(expf(-fabsf(v)));
}

__global__ void init_ws_k(float* __restrict__ acc, int* __restrict__ has_pos){
  int t = threadIdx.x;
  if (t < 8)  acc[t] = 0.0f;
  if (t < BB) has_pos[t] = 0;
}

// -------------------------------------------------------------------------
// Min-plus transform: out(x) = min_i [ f(i) + (x-i)^2 ]
//                            = x^2 + min_i [ (f(i)+i^2) - 2*i*x ]
// All values are integers < 2^24 -> fp32 exact, bit-identical to brute force.
// Block = 256 threads, covers 4 lines; group g=tid>>6 (wave-uniform) owns one
// line; lane computes 4 positions x = l, l+64, l+128, l+192 for BOTH arrays
// -> 8 independent min chains/thread, 4x fewer LDS reads per output.
// -------------------------------------------------------------------------

// Pass 1: per (b, column j): g(x,j) = min_i f(i,j) + (x-i)^2
// gA: seeds = pos (t>0.5) -> feeds d_in ; gB: seeds = ~pos -> feeds d_out
__global__ __launch_bounds__(256) void edt_pass1(const float* __restrict__ tgt,
                                                 float* __restrict__ gA,
                                                 float* __restrict__ gB,
                                                 int* __restrict__ has_pos){
  __shared__ __align__(16) float hp[4][HH];
  __shared__ __align__(16) float hn[4][HH];
  const int b  = blockIdx.x >> 6;
  const int j0 = (blockIdx.x & 63) << 2;
  const int t  = threadIdx.x;

  // stage: thread t = row i, 4 consecutive columns as float4
  const float4 tv = *(const float4*)&tgt[(b*HH + t)*WW + j0];
  const float i2 = (float)t * (float)t;
  hp[0][t] = (tv.x>0.5f ? 0.0f : INF_EDT) + i2;
  hn[0][t] = (tv.x>0.5f ? INF_EDT : 0.0f) + i2;
  hp[1][t] = (tv.y>0.5f ? 0.0f : INF_EDT) + i2;
  hn[1][t] = (tv.y>0.5f ? INF_EDT : 0.0f) + i2;
  hp[2][t] = (tv.z>0.5f ? 0.0f : INF_EDT) + i2;
  hn[2][t] = (tv.z>0.5f ? INF_EDT : 0.0f) + i2;
  hp[3][t] = (tv.w>0.5f ? 0.0f : INF_EDT) + i2;
  hn[3][t] = (tv.w>0.5f ? INF_EDT : 0.0f) + i2;
  const bool anyp = (tv.x>0.5f)||(tv.y>0.5f)||(tv.z>0.5f)||(tv.w>0.5f);
  unsigned long long bal = __ballot(anyp);
  if ((t & 63) == 0 && bal) atomicOr(&has_pos[b], 1);
  __syncthreads();

  const int g = t >> 6, l = t & 63;
  const float x0 = (float)l, x1 = (float)(l+64), x2 = (float)(l+128), x3 = (float)(l+192);
  float ap0=3.4e38f, ap1=3.4e38f, ap2=3.4e38f, ap3=3.4e38f;
  float an0=3.4e38f, an1=3.4e38f, an2=3.4e38f, an3=3.4e38f;
  const float4* hp4 = (const float4*)hp[g];
  const float4* hn4 = (const float4*)hn[g];
  float mjb = 0.0f;                       // -2*(4*it)
  #pragma unroll 4
  for (int it = 0; it < HH/4; ++it){
    float4 vp = hp4[it];                  // wave-uniform broadcast reads
    float4 vn = hn4[it];
    float m0 = mjb, m1 = mjb-2.0f, m2 = mjb-4.0f, m3 = mjb-6.0f;
    ap0=fminf(ap0,fmaf(m0,x0,vp.x)); ap1=fminf(ap1,fmaf(m0,x1,vp.x));
    ap2=fminf(ap2,fmaf(m0,x2,vp.x)); ap3=fminf(ap3,fmaf(m0,x3,vp.x));
    an0=fminf(an0,fmaf(m0,x0,vn.x)); an1=fminf(an1,fmaf(m0,x1,vn.x));
    an2=fminf(an2,fmaf(m0,x2,vn.x)); an3=fminf(an3,fmaf(m0,x3,vn.x));
    ap0=fminf(ap0,fmaf(m1,x0,vp.y)); ap1=fminf(ap1,fmaf(m1,x1,vp.y));
    ap2=fminf(ap2,fmaf(m1,x2,vp.y)); ap3=fminf(ap3,fmaf(m1,x3,vp.y));
    an0=fminf(an0,fmaf(m1,x0,vn.y)); an1=fminf(an1,fmaf(m1,x1,vn.y));
    an2=fminf(an2,fmaf(m1,x2,vn.y)); an3=fminf(an3,fmaf(m1,x3,vn.y));
    ap0=fminf(ap0,fmaf(m2,x0,vp.z)); ap1=fminf(ap1,fmaf(m2,x1,vp.z));
    ap2=fminf(ap2,fmaf(m2,x2,vp.z)); ap3=fminf(ap3,fmaf(m2,x3,vp.z));
    an0=fminf(an0,fmaf(m2,x0,vn.z)); an1=fminf(an1,fmaf(m2,x1,vn.z));
    an2=fminf(an2,fmaf(m2,x2,vn.z)); an3=fminf(an3,fmaf(m2,x3,vn.z));
    ap0=fminf(ap0,fmaf(m3,x0,vp.w)); ap1=fminf(ap1,fmaf(m3,x1,vp.w));
    ap2=fminf(ap2,fmaf(m3,x2,vp.w)); ap3=fminf(ap3,fmaf(m3,x3,vp.w));
    an0=fminf(an0,fmaf(m3,x0,vn.w)); an1=fminf(an1,fmaf(m3,x1,vn.w));
    an2=fminf(an2,fmaf(m3,x2,vn.w)); an3=fminf(an3,fmaf(m3,x3,vn.w));
    mjb -= 8.0f;
  }
  const int j = j0 + g;
  const int ob = b*HH*WW + j;
  gA[ob + (l    )*WW] = ap0 + x0*x0;  gB[ob + (l    )*WW] = an0 + x0*x0;
  gA[ob + (l+ 64)*WW] = ap1 + x1*x1;  gB[ob + (l+ 64)*WW] = an1 + x1*x1;
  gA[ob + (l+128)*WW] = ap2 + x2*x2;  gB[ob + (l+128)*WW] = an2 + x2*x2;
  gA[ob + (l+192)*WW] = ap3 + x3*x3;  gB[ob + (l+192)*WW] = an3 + x3*x3;
}

// Pass 2: per (b, row x): d2(x,y) = min_j g(x,j) + (y-j)^2 ; fused focal/ce/boundary.
__global__ __launch_bounds__(256) void edt_pass2_fused(const float* __restrict__ inp,
    const float* __restrict__ tgt, const float* __restrict__ gA, const float* __restrict__ gB,
    const int* __restrict__ has_pos, float* __restrict__ acc){
  __shared__ __align__(16) float ha[4][WW];
  __shared__ __align__(16) float hb[4][WW];
  __shared__ float red[3][4];
  const int b  = blockIdx.x >> 6;
  const int x0 = (blockIdx.x & 63) << 2;
  const int t  = threadIdx.x;

  // stage: h(j) = g(j) + j^2 ; thread t loads float4 of row r=t>>6 at j4=t&63 (coalesced)
  {
    const int r = t >> 6, j4 = t & 63;
    const int base = (b*HH + x0 + r)*WW + 4*j4;
    const float4 va = *(const float4*)&gA[base];
    const float4 vb = *(const float4*)&gB[base];
    const float jf = (float)(4*j4);
    ha[r][4*j4+0] = va.x + jf*jf;            hb[r][4*j4+0] = vb.x + jf*jf;
    ha[r][4*j4+1] = va.y + (jf+1)*(jf+1);    hb[r][4*j4+1] = vb.y + (jf+1)*(jf+1);
    ha[r][4*j4+2] = va.z + (jf+2)*(jf+2);    hb[r][4*j4+2] = vb.z + (jf+2)*(jf+2);
    ha[r][4*j4+3] = va.w + (jf+3)*(jf+3);    hb[r][4*j4+3] = vb.w + (jf+3)*(jf+3);
  }
  __syncthreads();

  const int g = t >> 6, l = t & 63;
  const int xr = x0 + g;                     // row this wave handles (uniform)
  const float y0 = (float)l, y1 = (float)(l+64), y2 = (float)(l+128), y3 = (float)(l+192);
  float dp0=3.4e38f, dp1=3.4e38f, dp2=3.4e38f, dp3=3.4e38f;
  float dn0=3.4e38f, dn1=3.4e38f, dn2=3.4e38f, dn3=3.4e38f;
  const float4* ha4 = (const float4*)ha[g];
  const float4* hb4 = (const float4*)hb[g];
  float mjb = 0.0f;
  #pragma unroll 4
  for (int it = 0; it < WW/4; ++it){
    float4 va = ha4[it];
    float4 vb = hb4[it];
    float m0 = mjb, m1 = mjb-2.0f, m2 = mjb-4.0f, m3 = mjb-6.0f;
    dp0=fminf(dp0,fmaf(m0,y0,va.x)); dp1=fminf(dp1,fmaf(m0,y1,va.x));
    dp2=fminf(dp2,fmaf(m0,y2,va.x)); dp3=fminf(dp3,fmaf(m0,y3,va.x));
    dn0=fminf(dn0,fmaf(m0,y0,vb.x)); dn1=fminf(dn1,fmaf(m0,y1,vb.x));
    dn2=fminf(dn2,fmaf(m0,y2,vb.x)); dn3=fminf(dn3,fmaf(m0,y3,vb.x));
    dp0=fminf(dp0,fmaf(m1,y0,va.y)); dp1=fminf(dp1,fmaf(m1,y1,va.y));
    dp2=fminf(dp2,fmaf(m1,y2,va.y)); dp3=fminf(dp3,fmaf(m1,y3,va.y));
    dn0=fminf(dn0,fmaf(m1,y0,vb.y)); dn1=fminf(dn1,fmaf(m1,y1,vb.y));
    dn2=fminf(dn2,fmaf(m1,y2,vb.y)); dn3=fminf(dn3,fmaf(m1,y3,vb.y));
    dp0=fminf(dp0,fmaf(m2,y0,va.z)); dp1=fminf(dp1,fmaf(m2,y1,va.z));
    dp2=fminf(dp2,fmaf(m2,y2,va.z)); dp3=fminf(dp3,fmaf(m2,y3,va.z));
    dn0=fminf(dn0,fmaf(m2,y0,vb.z)); dn1=fminf(dn1,fmaf(m2,y1,vb.z));
    dn2=fminf(dn2,fmaf(m2,y2,vb.z)); dn3=fminf(dn3,fmaf(m2,y3,vb.z));
    dp0=fminf(dp0,fmaf(m3,y0,va.w)); dp1=fminf(dp1,fmaf(m3,y1,va.w));
    dp2=fminf(dp2,fmaf(m3,y2,va.w)); dp3=fminf(dp3,fmaf(m3,y3,va.w));
    dn0=fminf(dn0,fmaf(m3,y0,vb.w)); dn1=fminf(dn1,fmaf(m3,y1,vb.w));
    dn2=fminf(dn2,fmaf(m3,y2,vb.w)); dn3=fminf(dn3,fmaf(m3,y3,vb.w));
    mjb -= 8.0f;
  }

  const int rowbase = (b*HH + xr)*WW;
  const int hp = has_pos[b];
  float s0 = 0.0f, s1 = 0.0f, s2 = 0.0f;   // focal, bce, boundary
  float dps[4] = {dp0+y0*y0, dp1+y1*y1, dp2+y2*y2, dp3+y3*y3};
  float dns[4] = {dn0+y0*y0, dn1+y1*y1, dn2+y2*y2, dn3+y3*y3};
  #pragma unroll
  for (int k = 0; k < 4; ++k){
    const int y = l + 64*k;
    const float xv = inp[rowbase + y];
    const float tv = tgt[rowbase + y];
    const float sg = sigmoidf(xv);
    float sdf = sqrtf(dns[k]) - sqrtf(dps[k]);   // d_out - d_in
    sdf = hp ? sdf : 0.0f;
    s2 += (sg - tv) * sdf;
    const float lp = logsigf(xv);
    const float ln = logsigf(-xv);
    const float bce = -(tv*lp + (1.0f - tv)*ln);
    const float pt = expf(-bce);
    const float om = 1.0f - pt;
    s0 += 0.8f * om * om * bce;                  // ALPHA=0.8, GAMMA=2
    s1 += bce;                                   // ce with POS_W=1 == bce
  }
  #pragma unroll
  for (int o = 32; o > 0; o >>= 1){
    s0 += __shfl_down(s0, o);
    s1 += __shfl_down(s1, o);
    s2 += __shfl_down(s2, o);
  }
  if (l == 0){ red[0][g]=s0; red[1][g]=s1; red[2][g]=s2; }
  __syncthreads();
  if (t == 0){
    atomicAdd(&acc[0], red[0][0]+red[0][1]+red[0][2]+red[0][3]);
    atomicAdd(&acc[1], red[1][0]+red[1][1]+red[1][2]+red[1][3]);
    atomicAdd(&acc[2], red[2][0]+red[2][1]+red[2][2]+red[2][3]);
  }
}

// Sobel edge term: mean |S(sigmoid(x)) - S(t)| with replicate padding.
__global__ __launch_bounds__(256) void sobel_edge_k(const float* __restrict__ inp,
    const float* __restrict__ tgt, float* __restrict__ acc){
  __shared__ float red[4];
  const int id = blockIdx.x*256 + threadIdx.x;
  const int b = id >> 16;
  const int r = (id >> 8) & 255;
  const int c = id & 255;
  const float* xb = inp + (b << 16);
  const float* tb = tgt + (b << 16);
  const int rm = r > 0 ? r-1 : 0, rp = r < 255 ? r+1 : 255;
  const int cm = c > 0 ? c-1 : 0, cp = c < 255 ? c+1 : 255;

  float s00 = sigmoidf(xb[rm*WW+cm]), s01 = sigmoidf(xb[rm*WW+c]), s02 = sigmoidf(xb[rm*WW+cp]);
  float s10 = sigmoidf(xb[ r*WW+cm]),                              s12 = sigmoidf(xb[ r*WW+cp]);
  float s20 = sigmoidf(xb[rp*WW+cm]), s21 = sigmoidf(xb[rp*WW+c]), s22 = sigmoidf(xb[rp*WW+cp]);
  float gxs = ((s02 - s00) + 2.0f*(s12 - s10) + (s22 - s20)) * 0.125f;
  float gys = ((s20 - s00) + 2.0f*(s21 - s01) + (s22 - s02)) * 0.125f;
  float mags = sqrtf(gxs*gxs + gys*gys + 1e-6f);

  float t00 = tb[rm*WW+cm], t01 = tb[rm*WW+c], t02 = tb[rm*WW+cp];
  float t10 = tb[ r*WW+cm],                    t12 = tb[ r*WW+cp];
  float t20 = tb[rp*WW+cm], t21 = tb[rp*WW+c], t22 = tb[rp*WW+cp];
  float gxt = ((t02 - t00) + 2.0f*(t12 - t10) + (t22 - t20)) * 0.125f;
  float gyt = ((t20 - t00) + 2.0f*(t21 - t01) + (t22 - t02)) * 0.125f;
  float magt = sqrtf(gxt*gxt + gyt*gyt + 1e-6f);

  float v = fabsf(mags - magt);
  #pragma unroll
  for (int o = 32; o > 0; o >>= 1) v += __shfl_down(v, o);
  if ((threadIdx.x & 63) == 0) red[threadIdx.x >> 6] = v;
  __syncthreads();
  if (threadIdx.x == 0) atomicAdd(&acc[3], red[0]+red[1]+red[2]+red[3]);
}

__global__ void finalize_k(const float* __restrict__ acc, float* __restrict__ out){
  out[0] = (acc[0] + acc[1] + acc[2] + acc[3]) * (1.0f/(float)NN);
}

extern "C" void kernel_launch(void* const* d_in, const int* in_sizes, int n_in,
                              void* d_out, int out_size, void* d_ws, size_t ws_size,
                              hipStream_t stream){
  const float* inp = (const float*)d_in[0];
  const float* tgt = (const float*)d_in[1];
  float* out = (float*)d_out;
  float* gA  = (float*)d_ws;          // B*H*W fp32, seeds = pos
  float* gB  = gA + NN;               // B*H*W fp32, seeds = ~pos
  float* acc = gB + NN;               // [focal, ce(bce), boundary, edge]
  int* has_pos = (int*)(acc + 8);     // B ints

  init_ws_k<<<1, 64, 0, stream>>>(acc, has_pos);
  edt_pass1<<<BB*(WW/4), 256, 0, stream>>>(tgt, gA, gB, has_pos);
  edt_pass2_fused<<<BB*(HH/4), 256, 0, stream>>>(inp, tgt, gA, gB, has_pos, acc);
  sobel_edge_k<<<NN/256, 256, 0, stream>>>(inp, tgt, acc);
  finalize_k<<<1, 1, 0, stream>>>(acc, out);
}

// Round 4
// 173.158 us; speedup vs baseline: 1.8972x; 1.2205x over previous
//
#include <hip/hip_runtime.h>
#include <math.h>

#define BB 16
#define HH 256
#define WW 256
#define NN (BB*HH*WW)
#define STH 4   // sobel rows per block

static __device__ constexpr float INF_EDT = 131072.0f; // H*H + W*W, exact in fp32

__device__ __forceinline__ float sigmoidf(float v){ return 1.0f/(1.0f+expf(-v)); }
// stable log_sigmoid(v) = min(v,0) - log1p(exp(-|v|))
__device__ __forceinline__ float logsigf(float v){
  return fminf(v, 0.0f) - log1pf(expf(-fabsf(v)));
}
__device__ __forceinline__ float min3f(float a, float b, float c){
  return fminf(fminf(a, b), c);   // clang fuses to v_min3_f32
}

__global__ void init_ws_k(float* __restrict__ acc, int* __restrict__ has_pos){
  int t = threadIdx.x;
  if (t < 8)  acc[t] = 0.0f;
  if (t < BB) has_pos[t] = 0;
}

// -------------------------------------------------------------------------
// Min-plus transform: out(x) = min_i [ f(i) + (x-i)^2 ]
//                            = x^2 + min_i [ (f(i)+i^2) - 2*i*x ]
// Integer-valued fp32 (< 2^24) -> bit-identical to the brute force reference.
// Block = 256 threads over 4 lines; wave g owns one line; lane computes 4
// positions for BOTH seed sets -> 8 independent min chains per thread.
// -------------------------------------------------------------------------

#define EDT_STEP(acc, xx, vv) \
  acc = min3f(acc, fmaf(m0,xx,vv.x), fmaf(m1,xx,vv.y)); \
  acc = min3f(acc, fmaf(m2,xx,vv.z), fmaf(m3,xx,vv.w))

// Pass 1: per (b, column j): g(x,j) = min_i f(i,j) + (x-i)^2
// gA: seeds = pos (t>0.5) -> feeds d_in ; gB: seeds = ~pos -> feeds d_out
__global__ __launch_bounds__(256) void edt_pass1(const float* __restrict__ tgt,
                                                 float* __restrict__ gA,
                                                 float* __restrict__ gB,
                                                 int* __restrict__ has_pos){
  __shared__ __align__(16) float hp[4][HH];
  __shared__ __align__(16) float hn[4][HH];
  const int b  = blockIdx.x >> 6;
  const int j0 = (blockIdx.x & 63) << 2;
  const int t  = threadIdx.x;

  // stage: thread t = row i, 4 consecutive columns as float4
  const float4 tv = *(const float4*)&tgt[(b*HH + t)*WW + j0];
  const float i2 = (float)t * (float)t;
  hp[0][t] = (tv.x>0.5f ? 0.0f : INF_EDT) + i2;
  hn[0][t] = (tv.x>0.5f ? INF_EDT : 0.0f) + i2;
  hp[1][t] = (tv.y>0.5f ? 0.0f : INF_EDT) + i2;
  hn[1][t] = (tv.y>0.5f ? INF_EDT : 0.0f) + i2;
  hp[2][t] = (tv.z>0.5f ? 0.0f : INF_EDT) + i2;
  hn[2][t] = (tv.z>0.5f ? INF_EDT : 0.0f) + i2;
  hp[3][t] = (tv.w>0.5f ? 0.0f : INF_EDT) + i2;
  hn[3][t] = (tv.w>0.5f ? INF_EDT : 0.0f) + i2;
  const bool anyp = (tv.x>0.5f)||(tv.y>0.5f)||(tv.z>0.5f)||(tv.w>0.5f);
  unsigned long long bal = __ballot(anyp);
  if ((t & 63) == 0 && bal) atomicOr(&has_pos[b], 1);
  __syncthreads();

  const int g = t >> 6, l = t & 63;
  const float x0 = (float)l, x1 = (float)(l+64), x2 = (float)(l+128), x3 = (float)(l+192);
  float ap0=3.4e38f, ap1=3.4e38f, ap2=3.4e38f, ap3=3.4e38f;
  float an0=3.4e38f, an1=3.4e38f, an2=3.4e38f, an3=3.4e38f;
  const float4* hp4 = (const float4*)hp[g];
  const float4* hn4 = (const float4*)hn[g];
  float mjb = 0.0f;                       // -2*(4*it)
  #pragma unroll 4
  for (int it = 0; it < HH/4; ++it){
    float4 vp = hp4[it];                  // wave-uniform broadcast reads
    float4 vn = hn4[it];
    float m0 = mjb, m1 = mjb-2.0f, m2 = mjb-4.0f, m3 = mjb-6.0f;
    EDT_STEP(ap0, x0, vp); EDT_STEP(ap1, x1, vp);
    EDT_STEP(ap2, x2, vp); EDT_STEP(ap3, x3, vp);
    EDT_STEP(an0, x0, vn); EDT_STEP(an1, x1, vn);
    EDT_STEP(an2, x2, vn); EDT_STEP(an3, x3, vn);
    mjb -= 8.0f;
  }
  const int j = j0 + g;
  const int ob = b*HH*WW + j;
  gA[ob + (l    )*WW] = ap0 + x0*x0;  gB[ob + (l    )*WW] = an0 + x0*x0;
  gA[ob + (l+ 64)*WW] = ap1 + x1*x1;  gB[ob + (l+ 64)*WW] = an1 + x1*x1;
  gA[ob + (l+128)*WW] = ap2 + x2*x2;  gB[ob + (l+128)*WW] = an2 + x2*x2;
  gA[ob + (l+192)*WW] = ap3 + x3*x3;  gB[ob + (l+192)*WW] = an3 + x3*x3;
}

// Pass 2: per (b, row x): d2(x,y) = min_j g(x,j) + (y-j)^2 ; fused focal/ce/boundary.
__global__ __launch_bounds__(256) void edt_pass2_fused(const float* __restrict__ inp,
    const float* __restrict__ tgt, const float* __restrict__ gA, const float* __restrict__ gB,
    const int* __restrict__ has_pos, float* __restrict__ acc){
  __shared__ __align__(16) float ha[4][WW];
  __shared__ __align__(16) float hb[4][WW];
  __shared__ float red[3][4];
  const int b  = blockIdx.x >> 6;
  const int x0 = (blockIdx.x & 63) << 2;
  const int t  = threadIdx.x;

  // stage: h(j) = g(j) + j^2 ; thread t loads float4 of row r=t>>6 at j4=t&63 (coalesced)
  {
    const int r = t >> 6, j4 = t & 63;
    const int base = (b*HH + x0 + r)*WW + 4*j4;
    const float4 va = *(const float4*)&gA[base];
    const float4 vb = *(const float4*)&gB[base];
    const float jf = (float)(4*j4);
    ha[r][4*j4+0] = va.x + jf*jf;            hb[r][4*j4+0] = vb.x + jf*jf;
    ha[r][4*j4+1] = va.y + (jf+1)*(jf+1);    hb[r][4*j4+1] = vb.y + (jf+1)*(jf+1);
    ha[r][4*j4+2] = va.z + (jf+2)*(jf+2);    hb[r][4*j4+2] = vb.z + (jf+2)*(jf+2);
    ha[r][4*j4+3] = va.w + (jf+3)*(jf+3);    hb[r][4*j4+3] = vb.w + (jf+3)*(jf+3);
  }
  __syncthreads();

  const int g = t >> 6, l = t & 63;
  const int xr = x0 + g;                     // row this wave handles (uniform)
  const float y0 = (float)l, y1 = (float)(l+64), y2 = (float)(l+128), y3 = (float)(l+192);
  float dp0=3.4e38f, dp1=3.4e38f, dp2=3.4e38f, dp3=3.4e38f;
  float dn0=3.4e38f, dn1=3.4e38f, dn2=3.4e38f, dn3=3.4e38f;
  const float4* ha4 = (const float4*)ha[g];
  const float4* hb4 = (const float4*)hb[g];
  float mjb = 0.0f;
  #pragma unroll 4
  for (int it = 0; it < WW/4; ++it){
    float4 va = ha4[it];
    float4 vb = hb4[it];
    float m0 = mjb, m1 = mjb-2.0f, m2 = mjb-4.0f, m3 = mjb-6.0f;
    EDT_STEP(dp0, y0, va); EDT_STEP(dp1, y1, va);
    EDT_STEP(dp2, y2, va); EDT_STEP(dp3, y3, va);
    EDT_STEP(dn0, y0, vb); EDT_STEP(dn1, y1, vb);
    EDT_STEP(dn2, y2, vb); EDT_STEP(dn3, y3, vb);
    mjb -= 8.0f;
  }

  const int rowbase = (b*HH + xr)*WW;
  const int hp = has_pos[b];
  float s0 = 0.0f, s1 = 0.0f, s2 = 0.0f;   // focal, bce, boundary
  float dps[4] = {dp0+y0*y0, dp1+y1*y1, dp2+y2*y2, dp3+y3*y3};
  float dns[4] = {dn0+y0*y0, dn1+y1*y1, dn2+y2*y2, dn3+y3*y3};
  #pragma unroll
  for (int k = 0; k < 4; ++k){
    const int y = l + 64*k;
    const float xv = inp[rowbase + y];
    const float tv = tgt[rowbase + y];
    const float sg = sigmoidf(xv);
    float sdf = sqrtf(dns[k]) - sqrtf(dps[k]);   // d_out - d_in
    sdf = hp ? sdf : 0.0f;
    s2 += (sg - tv) * sdf;
    const float lp = logsigf(xv);
    const float ln = logsigf(-xv);
    const float bce = -(tv*lp + (1.0f - tv)*ln);
    const float pt = expf(-bce);
    const float om = 1.0f - pt;
    s0 += 0.8f * om * om * bce;                  // ALPHA=0.8, GAMMA=2
    s1 += bce;                                   // ce with POS_W=1 == bce
  }
  #pragma unroll
  for (int o = 32; o > 0; o >>= 1){
    s0 += __shfl_down(s0, o);
    s1 += __shfl_down(s1, o);
    s2 += __shfl_down(s2, o);
  }
  if (l == 0){ red[0][g]=s0; red[1][g]=s1; red[2][g]=s2; }
  __syncthreads();
  if (t == 0){
    atomicAdd(&acc[0], red[0][0]+red[0][1]+red[0][2]+red[0][3]);
    atomicAdd(&acc[1], red[1][0]+red[1][1]+red[1][2]+red[1][3]);
    atomicAdd(&acc[2], red[2][0]+red[2][1]+red[2][2]+red[2][3]);
  }
}

// Sobel edge term: mean |S(sigmoid(x)) - S(t)| with replicate padding.
// LDS-tiled: stage sigmoid(x) and t for a (STH+2)-row strip once (float4
// coalesced, 1 expf per staged pixel), then each thread slides a 3x3
// register window down its column. LDS reads are stride-1 -> conflict-free.
__global__ __launch_bounds__(256) void sobel_edge_k(const float* __restrict__ inp,
    const float* __restrict__ tgt, float* __restrict__ acc){
  __shared__ __align__(16) float ss[STH+2][WW];
  __shared__ __align__(16) float tt[STH+2][WW];
  __shared__ float red[4];
  const int b  = blockIdx.x >> 6;            // H/STH = 64 strips per image
  const int r0 = (blockIdx.x & 63) * STH;
  const int t  = threadIdx.x;
  const int g = t >> 6, l = t & 63;

  for (int k = g; k < STH+2; k += 4){
    int gr = r0 - 1 + k; gr = gr < 0 ? 0 : (gr > HH-1 ? HH-1 : gr);
    const float4 xv = *(const float4*)&inp[(b*HH + gr)*WW + 4*l];
    const float4 tv = *(const float4*)&tgt[(b*HH + gr)*WW + 4*l];
    ss[k][4*l+0] = sigmoidf(xv.x); ss[k][4*l+1] = sigmoidf(xv.y);
    ss[k][4*l+2] = sigmoidf(xv.z); ss[k][4*l+3] = sigmoidf(xv.w);
    tt[k][4*l+0] = tv.x; tt[k][4*l+1] = tv.y;
    tt[k][4*l+2] = tv.z; tt[k][4*l+3] = tv.w;
  }
  __syncthreads();

  const int c = t;
  const int cm = c ? c-1 : 0, cp = c < WW-1 ? c+1 : WW-1;
  float a0m = ss[0][cm], a0c = ss[0][c], a0p = ss[0][cp];
  float a1m = ss[1][cm], a1c = ss[1][c], a1p = ss[1][cp];
  float b0m = tt[0][cm], b0c = tt[0][c], b0p = tt[0][cp];
  float b1m = tt[1][cm], b1c = tt[1][c], b1p = tt[1][cp];
  float v = 0.0f;
  #pragma unroll
  for (int rr = 0; rr < STH; ++rr){
    const float a2m = ss[rr+2][cm], a2c = ss[rr+2][c], a2p = ss[rr+2][cp];
    const float b2m = tt[rr+2][cm], b2c = tt[rr+2][c], b2p = tt[rr+2][cp];
    const float gxs = ((a0p-a0m) + 2.0f*(a1p-a1m) + (a2p-a2m)) * 0.125f;
    const float gys = ((a2m-a0m) + 2.0f*(a2c-a0c) + (a2p-a0p)) * 0.125f;
    const float mags = sqrtf(gxs*gxs + gys*gys + 1e-6f);
    const float gxt = ((b0p-b0m) + 2.0f*(b1p-b1m) + (b2p-b2m)) * 0.125f;
    const float gyt = ((b2m-b0m) + 2.0f*(b2c-b0c) + (b2p-b0p)) * 0.125f;
    const float magt = sqrtf(gxt*gxt + gyt*gyt + 1e-6f);
    v += fabsf(mags - magt);
    a0m=a1m; a0c=a1c; a0p=a1p; a1m=a2m; a1c=a2c; a1p=a2p;
    b0m=b1m; b0c=b1c; b0p=b1p; b1m=b2m; b1c=b2c; b1p=b2p;
  }
  #pragma unroll
  for (int o = 32; o > 0; o >>= 1) v += __shfl_down(v, o);
  if (l == 0) red[g] = v;
  __syncthreads();
  if (t == 0) atomicAdd(&acc[3], red[0]+red[1]+red[2]+red[3]);
}

__global__ void finalize_k(const float* __restrict__ acc, float* __restrict__ out){
  out[0] = (acc[0] + acc[1] + acc[2] + acc[3]) * (1.0f/(float)NN);
}

extern "C" void kernel_launch(void* const* d_in, const int* in_sizes, int n_in,
                              void* d_out, int out_size, void* d_ws, size_t ws_size,
                              hipStream_t stream){
  const float* inp = (const float*)d_in[0];
  const float* tgt = (const float*)d_in[1];
  float* out = (float*)d_out;
  float* gA  = (float*)d_ws;          // B*H*W fp32, seeds = pos
  float* gB  = gA + NN;               // B*H*W fp32, seeds = ~pos
  float* acc = gB + NN;               // [focal, ce(bce), boundary, edge]
  int* has_pos = (int*)(acc + 8);     // B ints

  init_ws_k<<<1, 64, 0, stream>>>(acc, has_pos);
  edt_pass1<<<BB*(WW/4), 256, 0, stream>>>(tgt, gA, gB, has_pos);
  edt_pass2_fused<<<BB*(HH/4), 256, 0, stream>>>(inp, tgt, gA, gB, has_pos, acc);
  sobel_edge_k<<<BB*(HH/STH), 256, 0, stream>>>(inp, tgt, acc);
  finalize_k<<<1, 1, 0, stream>>>(acc, out);
}